// Round 18
// baseline (582.792 us; speedup 1.0000x reference)
//
#include <hip/hip_runtime.h>
#include <math.h>

#define N 96
#define PAD 100        // padded LDS row stride (floats)
#define T 768          // 12 waves, one workgroup, one CU
#define ITERS 50
#define NORM_EVERY 10  // normalize on it%10==9 (incl. final it=49); f is
                       // degree-1 homogeneous so deferred norm is exact up
                       // to rounding; growth f32-safe
#define LW 52          // neighbor-list width (u16 entries, padded to x4)

typedef float f2 __attribute__((ext_vector_type(2)));
typedef unsigned int u32;
typedef u32 u2 __attribute__((ext_vector_type(2)));
typedef u32 u4 __attribute__((ext_vector_type(4)));
typedef unsigned short u16x4 __attribute__((ext_vector_type(4)));

// u32 max == float max for non-negative IEEE floats (all products here >= 0).
// Integer max chains fuse to v_max3_u32 (no NaN-semantics blocker).
__device__ __forceinline__ u32 um(u32 a, u32 b) { return a > b ? a : b; }

// lane-group max via DPP on u32 (VALU pipe); CTRL must be constexpr
template <int CTRL>
__device__ __forceinline__ u32 dppumax(u32 m) {
    int sw = __builtin_amdgcn_update_dpp((int)m, (int)m, CTRL, 0xf, 0xf, true);
    return um(m, (u32)sw);
}
#define DPP_XOR1 0xB1  // quad_perm:[1,0,3,2]
#define DPP_XOR2 0x4E  // quad_perm:[2,3,0,1]
#define DPP_SHL4 0x104 // row_shl:4 (dest l <- src l+4; OOB -> 0; data >= 0, ok)

// Fully fused MPM, one workgroup (r17 numerics + r10 low-DS tiling).
// M-phase: t = g*192 + cq*8 + q8 : g=row group (j≡g mod 4, 24 rows, wave-
//          uniform), cq=col quad (cols 4cq..4cq+3), q8=b-eighth (b in
//          [12q8,12q8+12)). W[4][6] f2 = 48 VGPRs. Per row: 3 const-offset
//          ds_read_b128 (half of r17), 24 v_pk_mul, per col 7 u32-max ops
//          (v_max3_u32) + 3 DPP (xor1,xor2,row_shl4); q8==0 writes b128.
// Agg:     ac=t%48 -> cols 2ac,2ac+1 ; rows i = t/48 + 16k (k=0..5);
//          f2 neighbor gathers via byte-offset lists; diag X in regs.
// Norm:    only on it%NORM_EVERY==NORM_EVERY-1 (3 barriers); else 2 barriers.
__global__ __launch_bounds__(T)
__attribute__((amdgpu_waves_per_eu(3, 3)))
void k_fused(const float* __restrict__ A,
             const float* __restrict__ vec,
             float* __restrict__ out) {
    __shared__ float Xs[N * PAD];            // 38400 B : X (staging B, then A)
    __shared__ float Ms[(N + 1) * PAD];      // 38800 B : full M + zero row 96
    __shared__ unsigned short lst[N * LW];   //  9984 B : nbr BYTE offsets (j*400)
    __shared__ short cnt4[N];                // padded counts (multiple of 4)
    __shared__ float degA[N];
    __shared__ float degB[N];
    __shared__ float red[T / 64];

    const int t = threadIdx.x;
    const int g = t / 192;                 // M row group 0..3 (wave-uniform)
    const int r8 = t % 192;
    const int cq = r8 >> 3;                // M col quad 0..23
    const int q8 = r8 & 7;                 // b-eighth
    const int ac = t % 48;                 // agg column-pair id
    const int ri = t / 48;                 // agg row base 0..15
    const float s1 = 1.0f / (1.0f + expf(-1.0f));   // sigmoid(1) = diag of B
    const float s1s1 = s1 * s1;

    // ---- setup phase 0: B -> Xs (staging) ----
#pragma unroll
    for (int k = 0; k < 12; ++k) {
        int e = t + k * T;
        int rr = e / N, cc = e % N;
        float logit;
        if (rr == cc) {
            logit = 1.0f;
        } else {
            int i = rr < cc ? rr : cc;
            int j = rr < cc ? cc : rr;
            int idx = i * 95 - (i * (i - 1)) / 2 + (j - i - 1);
            logit = vec[idx];
        }
        Xs[rr * PAD + cc] = 1.0f / (1.0f + expf(-logit));
    }
    __syncthreads();

    // W tiles as f2 pairs (B symmetric: col a == row a), diag = 0
    f2 Wq[4][6];
#pragma unroll
    for (int c = 0; c < 4; ++c) {
        int col = 4 * cq + c;
#pragma unroll
        for (int k = 0; k < 6; ++k) {
            int b = 12 * q8 + 2 * k;
            float w0 = (b == col) ? 0.f : Xs[b * PAD + col] * s1s1;
            float w1 = (b + 1 == col) ? 0.f : Xs[(b + 1) * PAD + col] * s1s1;
            Wq[c][k] = (f2){w0, w1};
        }
    }

    if (t < N) {
        float s = 0.f;
        for (int rr = 0; rr < N; ++rr) s += Xs[rr * PAD + t];
        degB[t] = s;
    }
    __syncthreads();   // all reads of B done

    // ---- setup phase 1: A -> Xs (staging) ----
#pragma unroll
    for (int k = 0; k < 12; ++k) {
        int e = t + k * T;
        Xs[(e / N) * PAD + (e % N)] = A[e];
    }
    __syncthreads();

    if (t < N) {
        float s = 0.f;
        for (int rr = 0; rr < N; ++rr) s += Xs[rr * PAD + t];   // A symmetric
        degA[t] = s;
    } else if (t < 2 * N) {
        int i = t - N;
        int c_ = 0;
        for (int j = 0; j < N; ++j) {
            if (j != i && Xs[j * PAD + i] > 0.5f)                // A symmetric
                lst[i * LW + c_++] = (unsigned short)(j * PAD * 4);
        }
        while (c_ & 3) lst[i * LW + c_++] = (unsigned short)(N * PAD * 4);
        cnt4[i] = (short)c_;
    }
    // zero row 96 of Ms (pad target) — written once, never overwritten
    if (t < PAD) Ms[N * PAD + t] = 0.0f;
    __syncthreads();   // lists/degs ready, Xs(A) reads done

    // node-sim coefficients + register-resident diag X (agg: 6 rows x 2 cols)
    f2 ns2[6], x2[6];
#pragma unroll
    for (int k = 0; k < 6; ++k) {
        int i = ri + 16 * k;
        ns2[k] = (f2){s1 / (fabsf(degA[i] - degB[2 * ac]) + 1.0f),
                      s1 / (fabsf(degA[i] - degB[2 * ac + 1]) + 1.0f)};
        x2[k] = (f2){1.0f / 96.0f, 1.0f / 96.0f};
    }

    // X0 = 1/96 everywhere (||X0|| = 1 exactly)
#pragma unroll
    for (int k = 0; k < 12; ++k) {
        int e = t + k * T;
        Xs[(e / N) * PAD + (e % N)] = (1.0f / 96.0f);
    }
    __syncthreads();

    const float* xbase = &Xs[g * PAD + 12 * q8];     // row jj -> + jj*4*PAD
    float* mbase = &Ms[g * PAD + 4 * cq];            // row jj -> + jj*4*PAD
    const char* MsaB = (const char*)Ms + 8 * ac;     // agg col-pair base (bytes)

    // ---- main loop ----
    for (int it = 0; it < ITERS; ++it) {
        // M-phase: 24 rows j = 4*jj + g, fully unrolled, const ds offsets
#pragma unroll
        for (int jj = 0; jj < 24; ++jj) {
            const float* xr = xbase + jj * 4 * PAD;
            float4 xv0 = *(const float4*)(xr);
            float4 xv1 = *(const float4*)(xr + 4);
            float4 xv2 = *(const float4*)(xr + 8);
            f2 xp0 = (f2){xv0.x, xv0.y}, xp1 = (f2){xv0.z, xv0.w};
            f2 xp2 = (f2){xv1.x, xv1.y}, xp3 = (f2){xv1.z, xv1.w};
            f2 xp4 = (f2){xv2.x, xv2.y}, xp5 = (f2){xv2.z, xv2.w};

            u32 mc[4];
#pragma unroll
            for (int c = 0; c < 4; ++c) {
                u2 u;
                u = __builtin_bit_cast(u2, Wq[c][0] * xp0);   // v_pk_mul_f32
                u32 e = um(u.x, u.y);
                u = __builtin_bit_cast(u2, Wq[c][1] * xp1);
                u32 o = um(u.x, u.y);
                u = __builtin_bit_cast(u2, Wq[c][2] * xp2);
                e = um(um(e, u.x), u.y);                      // v_max3_u32
                u = __builtin_bit_cast(u2, Wq[c][3] * xp3);
                o = um(um(o, u.x), u.y);
                u = __builtin_bit_cast(u2, Wq[c][4] * xp4);
                e = um(um(e, u.x), u.y);
                u = __builtin_bit_cast(u2, Wq[c][5] * xp5);
                o = um(um(o, u.x), u.y);
                u32 m = um(e, o);
                // exact 8-lane max combine, all on the VALU pipe
                m = dppumax<DPP_XOR1>(m);
                m = dppumax<DPP_XOR2>(m);
                m = dppumax<DPP_SHL4>(m);
                mc[c] = m;
            }
            if (q8 == 0)
                *(u4*)(mbase + jj * 4 * PAD) = (u4){mc[0], mc[1], mc[2], mc[3]};
        }
        __syncthreads();   // (A) Ms complete; all Xs reads done

        // aggregate (diag from regs, then ascending-j neighbors — exact order)
        f2 y2[6];
#pragma unroll
        for (int k = 0; k < 6; ++k) {
            int i = ri + 16 * k;
            f2 acc = x2[k] * ns2[k];
            int nch = (int)cnt4[i] >> 2;
            const unsigned short* lp = &lst[i * LW];
            for (int cc = 0; cc < nch; ++cc) {
                u16x4 o = *(const u16x4*)(lp + 4 * cc);
                acc += *(const f2*)(MsaB + o.x);
                acc += *(const f2*)(MsaB + o.y);
                acc += *(const f2*)(MsaB + o.z);
                acc += *(const f2*)(MsaB + o.w);
            }
            y2[k] = acc;
        }

        if ((it % NORM_EVERY) == NORM_EVERY - 1) {
            // block-wide norm (deterministic fixed tree); exact scale point
            float ss = 0.f;
#pragma unroll
            for (int k = 0; k < 6; ++k) {
                ss = fmaf(y2[k].x, y2[k].x, ss);
                ss = fmaf(y2[k].y, y2[k].y, ss);
            }
#pragma unroll
            for (int mm = 1; mm < 64; mm <<= 1) ss += __shfl_xor(ss, mm, 64);
            if ((t & 63) == 0) red[t >> 6] = ss;
            __syncthreads();   // (B) red ready; all Ms reads done
            float s = 0.f;
#pragma unroll
            for (int w2 = 0; w2 < T / 64; ++w2) s += red[w2];
            float inv = 1.0f / sqrtf(s);
            f2 inv2 = (f2){inv, inv};
#pragma unroll
            for (int k = 0; k < 6; ++k) {
                f2 xn = y2[k] * inv2;
                x2[k] = xn;
                *(f2*)&Xs[(ri + 16 * k) * PAD + 2 * ac] = xn;
            }
        } else {
            // deferred norm: write unnormalized (homogeneous iteration)
#pragma unroll
            for (int k = 0; k < 6; ++k) {
                x2[k] = y2[k];
                *(f2*)&Xs[(ri + 16 * k) * PAD + 2 * ac] = y2[k];
            }
        }
        __syncthreads();   // (C) Xs ready for next iter; Ms safe to overwrite
    }

    // ---- output (final iter was a norm iter: X is normalized) ----
#pragma unroll
    for (int k = 0; k < 12; ++k) {
        int e = t + k * T;
        out[e] = Xs[(e / N) * PAD + (e % N)];
    }
}

extern "C" void kernel_launch(void* const* d_in, const int* in_sizes, int n_in,
                              void* d_out, int out_size, void* d_ws, size_t ws_size,
                              hipStream_t stream) {
    const float* A = (const float*)d_in[0];     // A_gt, 96*96
    const float* vec = (const float*)d_in[1];   // vec_logits, 4560
    float* out = (float*)d_out;
    k_fused<<<1, T, 0, stream>>>(A, vec, out);
}

// Round 19
// 510.182 us; speedup vs baseline: 1.1423x; 1.1423x over previous
//
#include <hip/hip_runtime.h>
#include <math.h>

#define N 96
#define PAD 100        // padded LDS row stride (floats)
#define T 960          // 15 waves, one workgroup, one CU (4/4/4/3 per SIMD)
#define ITERS 50
#define NORM_EVERY 10  // normalize on it%10==9 (incl. final it=49); f is
                       // degree-1 homogeneous so deferred norm is exact up
                       // to rounding; growth f32-safe
#define LW 52          // neighbor-list width (u16 entries, padded to x4)

typedef float f2 __attribute__((ext_vector_type(2)));
typedef unsigned int u32;
typedef u32 u2 __attribute__((ext_vector_type(2)));
typedef unsigned short u16x4 __attribute__((ext_vector_type(4)));

// u32 max == float max for non-negative IEEE floats (all products here >= 0).
// Integer max chains fuse to v_max3_u32 (no NaN-semantics blocker).
__device__ __forceinline__ u32 um(u32 a, u32 b) { return a > b ? a : b; }

// lane-group max via DPP on u32 (VALU pipe); CTRL must be constexpr
template <int CTRL>
__device__ __forceinline__ u32 dppumax(u32 m) {
    int sw = __builtin_amdgcn_update_dpp((int)m, (int)m, CTRL, 0xf, 0xf, true);
    return um(m, (u32)sw);
}
#define DPP_XOR1 0xB1  // quad_perm:[1,0,3,2]
#define DPP_XOR2 0x4E  // quad_perm:[2,3,0,1]

// Fully fused MPM, one workgroup (r17 numerics, 15-wave occupancy).
// M-phase: t=(p<<2)|q : q=b-quarter (24 b), ap=p%48 -> cols a0=2ap,a0+1,
//          g=p/48 (0..4, wave-uniform) -> rows j≡g (mod 5): 20 rows for g=0,
//          19 otherwise. W as f2 pairs (48 regs); v_pk_mul; u32-max3 chains;
//          DPP quad combine; q==0 writes b64.
// Agg:     ac=t%48 -> cols 2ac,2ac+1 ; rows i = t/48 + 20k (k=0..4; k=4 only
//          for ri<16 — branchless via zero-extended cnt4 and x2[4]=0).
// Norm:    only on it%NORM_EVERY==NORM_EVERY-1 (3 barriers); else 2 barriers.
__global__ __launch_bounds__(T)
__attribute__((amdgpu_waves_per_eu(4, 4)))
void k_fused(const float* __restrict__ A,
             const float* __restrict__ vec,
             float* __restrict__ out) {
    __shared__ float Xs[N * PAD];            // 38400 B : X (staging B, then A)
    __shared__ float Ms[(N + 1) * PAD];      // 38800 B : full M + zero row 96
    __shared__ unsigned short lst[N * LW];   //  9984 B : nbr BYTE offsets (j*400)
    __shared__ short cnt4[104];              // counts (x4-padded); [96..103]=0
    __shared__ float degA[N];
    __shared__ float degB[N];
    __shared__ float red[T / 64];

    const int t = threadIdx.x;
    const int q = t & 3;                   // b-quarter
    const int p = t >> 2;
    const int ap = p % 48;                 // column-pair id (M-phase)
    const int g = p / 48;                  // row group 0..4 (wave-uniform)
    const int a0 = 2 * ap;
    const int ac = t % 48;                 // agg column-pair id
    const int ri = t / 48;                 // agg row base 0..19
    const int nrows = (g == 0) ? 20 : 19;  // rows j = g + 5*jj
    const float s1 = 1.0f / (1.0f + expf(-1.0f));   // sigmoid(1) = diag of B
    const float s1s1 = s1 * s1;

    // ---- setup phase 0: B -> Xs (staging) ----
#pragma unroll
    for (int k = 0; k < 10; ++k) {
        int e = t + k * T;
        if (e < N * N) {
            int rr = e / N, cc = e % N;
            float logit;
            if (rr == cc) {
                logit = 1.0f;
            } else {
                int i = rr < cc ? rr : cc;
                int j = rr < cc ? cc : rr;
                int idx = i * 95 - (i * (i - 1)) / 2 + (j - i - 1);
                logit = vec[idx];
            }
            Xs[rr * PAD + cc] = 1.0f / (1.0f + expf(-logit));
        }
    }
    __syncthreads();

    // W quarter-columns as f2 pairs (B symmetric: col a == row a), diag=0
    f2 Wp0[12], Wp1[12];
#pragma unroll
    for (int k = 0; k < 12; ++k) {
        int b = 24 * q + 2 * k;
        float w00 = Xs[b * PAD + a0] * s1s1;
        float w01 = Xs[(b + 1) * PAD + a0] * s1s1;
        float w10 = Xs[b * PAD + a0 + 1] * s1s1;
        float w11 = Xs[(b + 1) * PAD + a0 + 1] * s1s1;
        if (b == a0) w00 = 0.0f;
        if (b + 1 == a0) w01 = 0.0f;
        if (b == a0 + 1) w10 = 0.0f;
        if (b + 1 == a0 + 1) w11 = 0.0f;
        Wp0[k] = (f2){w00, w01};
        Wp1[k] = (f2){w10, w11};
    }

    if (t < N) {
        float s = 0.f;
        for (int rr = 0; rr < N; ++rr) s += Xs[rr * PAD + t];
        degB[t] = s;
    }
    __syncthreads();   // all reads of B done

    // ---- setup phase 1: A -> Xs (staging) ----
#pragma unroll
    for (int k = 0; k < 10; ++k) {
        int e = t + k * T;
        if (e < N * N) Xs[(e / N) * PAD + (e % N)] = A[e];
    }
    __syncthreads();

    if (t < N) {
        float s = 0.f;
        for (int rr = 0; rr < N; ++rr) s += Xs[rr * PAD + t];   // A symmetric
        degA[t] = s;
    } else if (t < 2 * N) {
        int i = t - N;
        int c_ = 0;
        for (int j = 0; j < N; ++j) {
            if (j != i && Xs[j * PAD + i] > 0.5f)                // A symmetric
                lst[i * LW + c_++] = (unsigned short)(j * PAD * 4);
        }
        while (c_ & 3) lst[i * LW + c_++] = (unsigned short)(N * PAD * 4);
        cnt4[i] = (short)c_;
    } else if (t < 2 * N + 8) {
        cnt4[N + (t - 2 * N)] = 0;        // zero-extend cnt4 to 104
    }
    // zero row 96 of Ms (pad target) — written once, never overwritten
    if (t < PAD) Ms[N * PAD + t] = 0.0f;
    __syncthreads();   // lists/degs ready, Xs(A) reads done

    // node-sim coefficients + register-resident diag X (agg: <=5 rows x 2 cols)
    f2 ns2[5], x2[5];
#pragma unroll
    for (int k = 0; k < 5; ++k) {
        int i = ri + 20 * k;
        int ic = i < N ? i : N - 1;       // clamp for safe degA read
        ns2[k] = (f2){s1 / (fabsf(degA[ic] - degB[2 * ac]) + 1.0f),
                      s1 / (fabsf(degA[ic] - degB[2 * ac + 1]) + 1.0f)};
        float x0v = (i < N) ? (1.0f / 96.0f) : 0.0f;
        x2[k] = (f2){x0v, x0v};
    }

    // X0 = 1/96 everywhere (||X0|| = 1 exactly)
#pragma unroll
    for (int k = 0; k < 10; ++k) {
        int e = t + k * T;
        if (e < N * N) Xs[(e / N) * PAD + (e % N)] = (1.0f / 96.0f);
    }
    __syncthreads();

    const float* xbase = &Xs[g * PAD + 24 * q];      // row jj -> + jj*5*PAD
    float* mbase = &Ms[g * PAD + a0];                // row jj -> + jj*5*PAD
    const char* MsaB = (const char*)Ms + 8 * ac;     // agg col-pair base (bytes)

    // ---- main loop ----
    for (int it = 0; it < ITERS; ++it) {
        // M-phase: rows j = 5*jj + g, fully unrolled, const ds offsets
#pragma unroll
        for (int jj = 0; jj < 20; ++jj) {
            if (jj < nrows) {             // wave-uniform guard (g uniform)
                const float* xr = xbase + jj * 5 * PAD;
                float4 xv0 = *(const float4*)(xr);
                float4 xv1 = *(const float4*)(xr + 4);
                float4 xv2 = *(const float4*)(xr + 8);
                float4 xv3 = *(const float4*)(xr + 12);
                float4 xv4 = *(const float4*)(xr + 16);
                float4 xv5 = *(const float4*)(xr + 20);
                f2 xp0  = (f2){xv0.x, xv0.y}, xp1  = (f2){xv0.z, xv0.w};
                f2 xp2  = (f2){xv1.x, xv1.y}, xp3  = (f2){xv1.z, xv1.w};
                f2 xp4  = (f2){xv2.x, xv2.y}, xp5  = (f2){xv2.z, xv2.w};
                f2 xp6  = (f2){xv3.x, xv3.y}, xp7  = (f2){xv3.z, xv3.w};
                f2 xp8  = (f2){xv4.x, xv4.y}, xp9  = (f2){xv4.z, xv4.w};
                f2 xp10 = (f2){xv5.x, xv5.y}, xp11 = (f2){xv5.z, xv5.w};

                u2 u;
                // col a0: 2 chains (even-k / odd-k), v_pk_mul + v_max3_u32
                u = __builtin_bit_cast(u2, Wp0[0] * xp0);
                u32 e0 = um(u.x, u.y);
                u = __builtin_bit_cast(u2, Wp0[1] * xp1);
                u32 o0 = um(u.x, u.y);
                u = __builtin_bit_cast(u2, Wp0[2]  * xp2);  e0 = um(um(e0, u.x), u.y);
                u = __builtin_bit_cast(u2, Wp0[3]  * xp3);  o0 = um(um(o0, u.x), u.y);
                u = __builtin_bit_cast(u2, Wp0[4]  * xp4);  e0 = um(um(e0, u.x), u.y);
                u = __builtin_bit_cast(u2, Wp0[5]  * xp5);  o0 = um(um(o0, u.x), u.y);
                u = __builtin_bit_cast(u2, Wp0[6]  * xp6);  e0 = um(um(e0, u.x), u.y);
                u = __builtin_bit_cast(u2, Wp0[7]  * xp7);  o0 = um(um(o0, u.x), u.y);
                u = __builtin_bit_cast(u2, Wp0[8]  * xp8);  e0 = um(um(e0, u.x), u.y);
                u = __builtin_bit_cast(u2, Wp0[9]  * xp9);  o0 = um(um(o0, u.x), u.y);
                u = __builtin_bit_cast(u2, Wp0[10] * xp10); e0 = um(um(e0, u.x), u.y);
                u = __builtin_bit_cast(u2, Wp0[11] * xp11); o0 = um(um(o0, u.x), u.y);
                u32 m0 = um(e0, o0);

                // col a0+1
                u = __builtin_bit_cast(u2, Wp1[0] * xp0);
                u32 e1 = um(u.x, u.y);
                u = __builtin_bit_cast(u2, Wp1[1] * xp1);
                u32 o1 = um(u.x, u.y);
                u = __builtin_bit_cast(u2, Wp1[2]  * xp2);  e1 = um(um(e1, u.x), u.y);
                u = __builtin_bit_cast(u2, Wp1[3]  * xp3);  o1 = um(um(o1, u.x), u.y);
                u = __builtin_bit_cast(u2, Wp1[4]  * xp4);  e1 = um(um(e1, u.x), u.y);
                u = __builtin_bit_cast(u2, Wp1[5]  * xp5);  o1 = um(um(o1, u.x), u.y);
                u = __builtin_bit_cast(u2, Wp1[6]  * xp6);  e1 = um(um(e1, u.x), u.y);
                u = __builtin_bit_cast(u2, Wp1[7]  * xp7);  o1 = um(um(o1, u.x), u.y);
                u = __builtin_bit_cast(u2, Wp1[8]  * xp8);  e1 = um(um(e1, u.x), u.y);
                u = __builtin_bit_cast(u2, Wp1[9]  * xp9);  o1 = um(um(o1, u.x), u.y);
                u = __builtin_bit_cast(u2, Wp1[10] * xp10); e1 = um(um(e1, u.x), u.y);
                u = __builtin_bit_cast(u2, Wp1[11] * xp11); o1 = um(um(o1, u.x), u.y);
                u32 m1 = um(e1, o1);

                // combine b-quarters across the lane quad (exact, VALU pipe)
                m0 = dppumax<DPP_XOR1>(m0);
                m0 = dppumax<DPP_XOR2>(m0);
                m1 = dppumax<DPP_XOR1>(m1);
                m1 = dppumax<DPP_XOR2>(m1);
                if (q == 0)
                    *(u2*)(mbase + jj * 5 * PAD) = (u2){m0, m1};
            }
        }
        __syncthreads();   // (A) Ms complete; all Xs reads done

        // aggregate (diag from regs, then ascending-j neighbors — exact order)
        f2 y2[5];
#pragma unroll
        for (int k = 0; k < 5; ++k) {
            int i = ri + 20 * k;                 // i<104; cnt4[i>=96]==0
            f2 acc = x2[k] * ns2[k];             // 0 for invalid lanes
            int nch = (int)cnt4[i] >> 2;
            const unsigned short* lp = &lst[(i < N ? i : 0) * LW];
            for (int cc = 0; cc < nch; ++cc) {
                u16x4 o = *(const u16x4*)(lp + 4 * cc);
                acc += *(const f2*)(MsaB + o.x);
                acc += *(const f2*)(MsaB + o.y);
                acc += *(const f2*)(MsaB + o.z);
                acc += *(const f2*)(MsaB + o.w);
            }
            y2[k] = acc;
        }

        if ((it % NORM_EVERY) == NORM_EVERY - 1) {
            // block-wide norm (deterministic fixed tree); exact scale point
            float ss = 0.f;
#pragma unroll
            for (int k = 0; k < 5; ++k) {
                ss = fmaf(y2[k].x, y2[k].x, ss);
                ss = fmaf(y2[k].y, y2[k].y, ss);
            }
#pragma unroll
            for (int mm = 1; mm < 64; mm <<= 1) ss += __shfl_xor(ss, mm, 64);
            if ((t & 63) == 0) red[t >> 6] = ss;
            __syncthreads();   // (B) red ready; all Ms reads done
            float s = 0.f;
#pragma unroll
            for (int w2 = 0; w2 < T / 64; ++w2) s += red[w2];
            float inv = 1.0f / sqrtf(s);
            f2 inv2 = (f2){inv, inv};
#pragma unroll
            for (int k = 0; k < 5; ++k) {
                int i = ri + 20 * k;
                f2 xn = y2[k] * inv2;
                x2[k] = xn;
                if (i < N) *(f2*)&Xs[i * PAD + 2 * ac] = xn;
            }
        } else {
            // deferred norm: write unnormalized (homogeneous iteration)
#pragma unroll
            for (int k = 0; k < 5; ++k) {
                int i = ri + 20 * k;
                x2[k] = y2[k];
                if (i < N) *(f2*)&Xs[i * PAD + 2 * ac] = y2[k];
            }
        }
        __syncthreads();   // (C) Xs ready for next iter; Ms safe to overwrite
    }

    // ---- output (final iter was a norm iter: X is normalized) ----
#pragma unroll
    for (int k = 0; k < 10; ++k) {
        int e = t + k * T;
        if (e < N * N) out[e] = Xs[(e / N) * PAD + (e % N)];
    }
}

extern "C" void kernel_launch(void* const* d_in, const int* in_sizes, int n_in,
                              void* d_out, int out_size, void* d_ws, size_t ws_size,
                              hipStream_t stream) {
    const float* A = (const float*)d_in[0];     // A_gt, 96*96
    const float* vec = (const float*)d_in[1];   // vec_logits, 4560
    float* out = (float*)d_out;
    k_fused<<<1, T, 0, stream>>>(A, vec, out);
}

// Round 21
// 510.050 us; speedup vs baseline: 1.1426x; 1.0003x over previous
//
#include <hip/hip_runtime.h>
#include <math.h>

#define N 96
#define PAD 100        // padded LDS row stride (floats)
#define T 960          // 15 waves, one workgroup, one CU (HW max block = 1024)
#define ITERS 50
#define NORM_EVERY 10  // normalize on it%10==9 (incl. final it=49); f is
                       // degree-1 homogeneous so deferred norm is exact up
                       // to rounding; growth f32-safe
#define LW 52          // neighbor-list width (u16 entries, padded to x4)

typedef float f2 __attribute__((ext_vector_type(2)));
typedef unsigned int u32;
typedef u32 u2 __attribute__((ext_vector_type(2)));
typedef unsigned short u16x4 __attribute__((ext_vector_type(4)));

// u32 max == float max for non-negative IEEE floats (all products here >= 0).
// Integer max chains fuse to v_max3_u32 (no NaN-semantics blocker).
__device__ __forceinline__ u32 um(u32 a, u32 b) { return a > b ? a : b; }

// lane-group max via DPP on u32 (VALU pipe); CTRL must be constexpr
template <int CTRL>
__device__ __forceinline__ u32 dppumax(u32 m) {
    int sw = __builtin_amdgcn_update_dpp((int)m, (int)m, CTRL, 0xf, 0xf, true);
    return um(m, (u32)sw);
}
#define DPP_XOR1 0xB1  // quad_perm:[1,0,3,2]
#define DPP_XOR2 0x4E  // quad_perm:[2,3,0,1]

// Fully fused MPM, one workgroup (r17 numerics, 15-wave occupancy).
// M-phase: t=(p<<2)|q : q=b-quarter (24 b), ap=p%48 -> cols a0=2ap,a0+1,
//          g=p/48 (0..4, wave-uniform) -> rows j≡g (mod 5): 20 rows for g=0,
//          19 otherwise. W as f2 pairs (48 regs); v_pk_mul; u32-max3 chains;
//          DPP quad combine; q==0 writes b64.
// Agg:     ac=t%48 -> cols 2ac,2ac+1 ; rows i = t/48 + 20k (k=0..4; k=4 only
//          for ri<16 — branchless via zero-extended cnt4 and x2[4]=0).
// Norm:    only on it%NORM_EVERY==NORM_EVERY-1 (3 barriers); else 2 barriers.
__global__ __launch_bounds__(T)
__attribute__((amdgpu_waves_per_eu(4, 4)))
void k_fused(const float* __restrict__ A,
             const float* __restrict__ vec,
             float* __restrict__ out) {
    __shared__ float Xs[N * PAD];            // 38400 B : X (staging B, then A)
    __shared__ float Ms[(N + 1) * PAD];      // 38800 B : full M + zero row 96
    __shared__ unsigned short lst[N * LW];   //  9984 B : nbr BYTE offsets (j*400)
    __shared__ short cnt4[104];              // counts (x4-padded); [96..103]=0
    __shared__ float degA[N];
    __shared__ float degB[N];
    __shared__ float red[T / 64];

    const int t = threadIdx.x;
    const int q = t & 3;                   // b-quarter
    const int p = t >> 2;
    const int ap = p % 48;                 // column-pair id (M-phase)
    const int g = p / 48;                  // row group 0..4 (wave-uniform)
    const int a0 = 2 * ap;
    const int ac = t % 48;                 // agg column-pair id
    const int ri = t / 48;                 // agg row base 0..19
    const int nrows = (g == 0) ? 20 : 19;  // rows j = g + 5*jj
    const float s1 = 1.0f / (1.0f + expf(-1.0f));   // sigmoid(1) = diag of B
    const float s1s1 = s1 * s1;

    // ---- setup phase 0: B -> Xs (staging) ----
#pragma unroll
    for (int k = 0; k < 10; ++k) {
        int e = t + k * T;
        if (e < N * N) {
            int rr = e / N, cc = e % N;
            float logit;
            if (rr == cc) {
                logit = 1.0f;
            } else {
                int i = rr < cc ? rr : cc;
                int j = rr < cc ? cc : rr;
                int idx = i * 95 - (i * (i - 1)) / 2 + (j - i - 1);
                logit = vec[idx];
            }
            Xs[rr * PAD + cc] = 1.0f / (1.0f + expf(-logit));
        }
    }
    __syncthreads();

    // W quarter-columns as f2 pairs (B symmetric: col a == row a), diag=0
    f2 Wp0[12], Wp1[12];
#pragma unroll
    for (int k = 0; k < 12; ++k) {
        int b = 24 * q + 2 * k;
        float w00 = Xs[b * PAD + a0] * s1s1;
        float w01 = Xs[(b + 1) * PAD + a0] * s1s1;
        float w10 = Xs[b * PAD + a0 + 1] * s1s1;
        float w11 = Xs[(b + 1) * PAD + a0 + 1] * s1s1;
        if (b == a0) w00 = 0.0f;
        if (b + 1 == a0) w01 = 0.0f;
        if (b == a0 + 1) w10 = 0.0f;
        if (b + 1 == a0 + 1) w11 = 0.0f;
        Wp0[k] = (f2){w00, w01};
        Wp1[k] = (f2){w10, w11};
    }

    if (t < N) {
        float s = 0.f;
        for (int rr = 0; rr < N; ++rr) s += Xs[rr * PAD + t];
        degB[t] = s;
    }
    __syncthreads();   // all reads of B done

    // ---- setup phase 1: A -> Xs (staging) ----
#pragma unroll
    for (int k = 0; k < 10; ++k) {
        int e = t + k * T;
        if (e < N * N) Xs[(e / N) * PAD + (e % N)] = A[e];
    }
    __syncthreads();

    if (t < N) {
        float s = 0.f;
        for (int rr = 0; rr < N; ++rr) s += Xs[rr * PAD + t];   // A symmetric
        degA[t] = s;
    } else if (t < 2 * N) {
        int i = t - N;
        int c_ = 0;
        for (int j = 0; j < N; ++j) {
            if (j != i && Xs[j * PAD + i] > 0.5f)                // A symmetric
                lst[i * LW + c_++] = (unsigned short)(j * PAD * 4);
        }
        while (c_ & 3) lst[i * LW + c_++] = (unsigned short)(N * PAD * 4);
        cnt4[i] = (short)c_;
    } else if (t < 2 * N + 8) {
        cnt4[N + (t - 2 * N)] = 0;        // zero-extend cnt4 to 104
    }
    // zero row 96 of Ms (pad target) — written once, never overwritten
    if (t < PAD) Ms[N * PAD + t] = 0.0f;
    __syncthreads();   // lists/degs ready, Xs(A) reads done

    // node-sim coefficients + register-resident diag X (agg: <=5 rows x 2 cols)
    f2 ns2[5], x2[5];
#pragma unroll
    for (int k = 0; k < 5; ++k) {
        int i = ri + 20 * k;
        int ic = i < N ? i : N - 1;       // clamp for safe degA read
        ns2[k] = (f2){s1 / (fabsf(degA[ic] - degB[2 * ac]) + 1.0f),
                      s1 / (fabsf(degA[ic] - degB[2 * ac + 1]) + 1.0f)};
        float x0v = (i < N) ? (1.0f / 96.0f) : 0.0f;
        x2[k] = (f2){x0v, x0v};
    }

    // X0 = 1/96 everywhere (||X0|| = 1 exactly)
#pragma unroll
    for (int k = 0; k < 10; ++k) {
        int e = t + k * T;
        if (e < N * N) Xs[(e / N) * PAD + (e % N)] = (1.0f / 96.0f);
    }
    __syncthreads();

    const float* xbase = &Xs[g * PAD + 24 * q];      // row jj -> + jj*5*PAD
    float* mbase = &Ms[g * PAD + a0];                // row jj -> + jj*5*PAD
    const char* MsaB = (const char*)Ms + 8 * ac;     // agg col-pair base (bytes)

    // ---- main loop ----
    for (int it = 0; it < ITERS; ++it) {
        // M-phase: rows j = 5*jj + g, fully unrolled, const ds offsets
#pragma unroll
        for (int jj = 0; jj < 20; ++jj) {
            if (jj < nrows) {             // wave-uniform guard (g uniform)
                const float* xr = xbase + jj * 5 * PAD;
                float4 xv0 = *(const float4*)(xr);
                float4 xv1 = *(const float4*)(xr + 4);
                float4 xv2 = *(const float4*)(xr + 8);
                float4 xv3 = *(const float4*)(xr + 12);
                float4 xv4 = *(const float4*)(xr + 16);
                float4 xv5 = *(const float4*)(xr + 20);
                f2 xp0  = (f2){xv0.x, xv0.y}, xp1  = (f2){xv0.z, xv0.w};
                f2 xp2  = (f2){xv1.x, xv1.y}, xp3  = (f2){xv1.z, xv1.w};
                f2 xp4  = (f2){xv2.x, xv2.y}, xp5  = (f2){xv2.z, xv2.w};
                f2 xp6  = (f2){xv3.x, xv3.y}, xp7  = (f2){xv3.z, xv3.w};
                f2 xp8  = (f2){xv4.x, xv4.y}, xp9  = (f2){xv4.z, xv4.w};
                f2 xp10 = (f2){xv5.x, xv5.y}, xp11 = (f2){xv5.z, xv5.w};

                u2 u;
                // col a0: 2 chains (even-k / odd-k), v_pk_mul + v_max3_u32
                u = __builtin_bit_cast(u2, Wp0[0] * xp0);
                u32 e0 = um(u.x, u.y);
                u = __builtin_bit_cast(u2, Wp0[1] * xp1);
                u32 o0 = um(u.x, u.y);
                u = __builtin_bit_cast(u2, Wp0[2]  * xp2);  e0 = um(um(e0, u.x), u.y);
                u = __builtin_bit_cast(u2, Wp0[3]  * xp3);  o0 = um(um(o0, u.x), u.y);
                u = __builtin_bit_cast(u2, Wp0[4]  * xp4);  e0 = um(um(e0, u.x), u.y);
                u = __builtin_bit_cast(u2, Wp0[5]  * xp5);  o0 = um(um(o0, u.x), u.y);
                u = __builtin_bit_cast(u2, Wp0[6]  * xp6);  e0 = um(um(e0, u.x), u.y);
                u = __builtin_bit_cast(u2, Wp0[7]  * xp7);  o0 = um(um(o0, u.x), u.y);
                u = __builtin_bit_cast(u2, Wp0[8]  * xp8);  e0 = um(um(e0, u.x), u.y);
                u = __builtin_bit_cast(u2, Wp0[9]  * xp9);  o0 = um(um(o0, u.x), u.y);
                u = __builtin_bit_cast(u2, Wp0[10] * xp10); e0 = um(um(e0, u.x), u.y);
                u = __builtin_bit_cast(u2, Wp0[11] * xp11); o0 = um(um(o0, u.x), u.y);
                u32 m0 = um(e0, o0);

                // col a0+1
                u = __builtin_bit_cast(u2, Wp1[0] * xp0);
                u32 e1 = um(u.x, u.y);
                u = __builtin_bit_cast(u2, Wp1[1] * xp1);
                u32 o1 = um(u.x, u.y);
                u = __builtin_bit_cast(u2, Wp1[2]  * xp2);  e1 = um(um(e1, u.x), u.y);
                u = __builtin_bit_cast(u2, Wp1[3]  * xp3);  o1 = um(um(o1, u.x), u.y);
                u = __builtin_bit_cast(u2, Wp1[4]  * xp4);  e1 = um(um(e1, u.x), u.y);
                u = __builtin_bit_cast(u2, Wp1[5]  * xp5);  o1 = um(um(o1, u.x), u.y);
                u = __builtin_bit_cast(u2, Wp1[6]  * xp6);  e1 = um(um(e1, u.x), u.y);
                u = __builtin_bit_cast(u2, Wp1[7]  * xp7);  o1 = um(um(o1, u.x), u.y);
                u = __builtin_bit_cast(u2, Wp1[8]  * xp8);  e1 = um(um(e1, u.x), u.y);
                u = __builtin_bit_cast(u2, Wp1[9]  * xp9);  o1 = um(um(o1, u.x), u.y);
                u = __builtin_bit_cast(u2, Wp1[10] * xp10); e1 = um(um(e1, u.x), u.y);
                u = __builtin_bit_cast(u2, Wp1[11] * xp11); o1 = um(um(o1, u.x), u.y);
                u32 m1 = um(e1, o1);

                // combine b-quarters across the lane quad (exact, VALU pipe)
                m0 = dppumax<DPP_XOR1>(m0);
                m0 = dppumax<DPP_XOR2>(m0);
                m1 = dppumax<DPP_XOR1>(m1);
                m1 = dppumax<DPP_XOR2>(m1);
                if (q == 0)
                    *(u2*)(mbase + jj * 5 * PAD) = (u2){m0, m1};
            }
        }
        __syncthreads();   // (A) Ms complete; all Xs reads done

        // aggregate (diag from regs, then ascending-j neighbors — exact order)
        f2 y2[5];
#pragma unroll
        for (int k = 0; k < 5; ++k) {
            int i = ri + 20 * k;                 // i<104; cnt4[i>=96]==0
            f2 acc = x2[k] * ns2[k];             // 0 for invalid lanes
            int nch = (int)cnt4[i] >> 2;
            const unsigned short* lp = &lst[(i < N ? i : 0) * LW];
            for (int cc = 0; cc < nch; ++cc) {
                u16x4 o = *(const u16x4*)(lp + 4 * cc);
                acc += *(const f2*)(MsaB + o.x);
                acc += *(const f2*)(MsaB + o.y);
                acc += *(const f2*)(MsaB + o.z);
                acc += *(const f2*)(MsaB + o.w);
            }
            y2[k] = acc;
        }

        if ((it % NORM_EVERY) == NORM_EVERY - 1) {
            // block-wide norm (deterministic fixed tree); exact scale point
            float ss = 0.f;
#pragma unroll
            for (int k = 0; k < 5; ++k) {
                ss = fmaf(y2[k].x, y2[k].x, ss);
                ss = fmaf(y2[k].y, y2[k].y, ss);
            }
#pragma unroll
            for (int mm = 1; mm < 64; mm <<= 1) ss += __shfl_xor(ss, mm, 64);
            if ((t & 63) == 0) red[t >> 6] = ss;
            __syncthreads();   // (B) red ready; all Ms reads done
            float s = 0.f;
#pragma unroll
            for (int w2 = 0; w2 < T / 64; ++w2) s += red[w2];
            float inv = 1.0f / sqrtf(s);
            f2 inv2 = (f2){inv, inv};
#pragma unroll
            for (int k = 0; k < 5; ++k) {
                int i = ri + 20 * k;
                f2 xn = y2[k] * inv2;
                x2[k] = xn;
                if (i < N) *(f2*)&Xs[i * PAD + 2 * ac] = xn;
            }
        } else {
            // deferred norm: write unnormalized (homogeneous iteration)
#pragma unroll
            for (int k = 0; k < 5; ++k) {
                int i = ri + 20 * k;
                x2[k] = y2[k];
                if (i < N) *(f2*)&Xs[i * PAD + 2 * ac] = y2[k];
            }
        }
        __syncthreads();   // (C) Xs ready for next iter; Ms safe to overwrite
    }

    // ---- output (final iter was a norm iter: X is normalized) ----
#pragma unroll
    for (int k = 0; k < 10; ++k) {
        int e = t + k * T;
        if (e < N * N) out[e] = Xs[(e / N) * PAD + (e % N)];
    }
}

extern "C" void kernel_launch(void* const* d_in, const int* in_sizes, int n_in,
                              void* d_out, int out_size, void* d_ws, size_t ws_size,
                              hipStream_t stream) {
    const float* A = (const float*)d_in[0];     // A_gt, 96*96
    const float* vec = (const float*)d_in[1];   // vec_logits, 4560
    float* out = (float*)d_out;
    k_fused<<<1, T, 0, stream>>>(A, vec, out);
}